// Round 3
// baseline (4679.996 us; speedup 1.0000x reference)
//
#include <hip/hip_runtime.h>
#include <hip/hip_bf16.h>
#include <math.h>

#define B_ 512
#define S_ 256
#define D_ 256
#define NLOC 50000
#define KX 448      // D + TEMP
#define G4 1024
#define NEGV -1000000000.0f
#define NBLK 128    // persistent LSTM blocks (16 batch-tiles x 8 d-tiles)

typedef __attribute__((ext_vector_type(8))) short short8;
typedef __attribute__((ext_vector_type(4))) float f32x4;

__device__ __forceinline__ float sigmoidf_(float x){ return 1.0f/(1.0f+expf(-x)); }
__device__ __forceinline__ float geluf_(float x){ return 0.5f*x*(1.0f+erff(x*0.70710678118654752f)); }
__device__ __forceinline__ unsigned short f2bf_(float x){
  __hip_bfloat16 h = __float2bfloat16(x);
  return *(unsigned short*)&h;
}
__device__ __forceinline__ float bf2f_(unsigned short u){
  __hip_bfloat16 h = *(__hip_bfloat16*)&u;
  return __bfloat162float(h);
}

// ---- init: zero hbf0 (bf16), barrier flags, detect-flag ----
__global__ void k_init(unsigned short* hbf, int* flags, int* flag){
  int i = blockIdx.x*256 + threadIdx.x;
  if (i < B_*D_) hbf[i]=0;
  if (i < NBLK*16) flags[i]=0;
  if (i==0) *flag = 0;
}

// ---- detect mask layout: any nonzero odd byte in first B*S bytes => uint8 ----
__global__ void k_detect(const unsigned char* m, int* flag){
  int i = blockIdx.x*256 + threadIdx.x;
  if ((i & 1) && i < B_*S_ && m[i]) atomicOr(flag, 1);
}

// ---- seq_lens[b] = count(mask row) - 1 ----
__global__ void k_seqlen(const void* mp, const int* flag, int* slens){
  int b = blockIdx.x*256 + threadIdx.x;
  if (b >= B_) return;
  int cnt = 0;
  if (*flag){
    const unsigned char* m = (const unsigned char*)mp;
    for (int s=0;s<S_;s++) cnt += (m[b*S_+s] != 0);
  } else {
    const int* m = (const int*)mp;
    for (int s=0;s<S_;s++) cnt += (m[b*S_+s] != 0);
  }
  slens[b] = cnt - 1;
}

// ---- convert W_ih, W_hh to bf16; btot = b_ih + b_hh ----
__global__ void k_buildw(const float* wih, const float* whh, const float* bih,
                         const float* bhh, unsigned short* Wihbf,
                         unsigned short* Whhbf, float* btot){
  int i = blockIdx.x*256 + threadIdx.x;
  if (i < G4*KX) Wihbf[i] = f2bf_(wih[i]);
  if (i < G4*D_) Whhbf[i] = f2bf_(whh[i]);
  if (i < G4) btot[i] = bih[i] + bhh[i];
}

// ---- Gx = X @ W_ih^T + btot, stored [t][b][1024] bf16. X gathered on the fly. ----
// grid (8, 1024): x = N-tile (128 cols), y = M-tile (128 rows of b*S+t). 4 waves.
__global__ __launch_bounds__(256) void k_gx(
    const int* __restrict__ loc, const int* __restrict__ usr,
    const int* __restrict__ wdy, const int* __restrict__ sm,
    const float* __restrict__ loct, const float* __restrict__ usert,
    const float* __restrict__ hourt, const float* __restrict__ wdt,
    const unsigned short* __restrict__ Wihbf, const float* __restrict__ btot,
    unsigned short* __restrict__ Gx){
  __shared__ unsigned short As[128][40];
  int tid = threadIdx.x;
  int n0 = blockIdx.x*128, m0 = blockIdx.y*128;
  int w = tid>>6, lane = tid&63;
  int quad = lane>>4, l16 = lane&15;
  int mw = (w>>1)*64, nw = (w&1)*64;
  f32x4 acc[4][4] = {};
  int r0 = tid>>2, seg = tid&3;
  for (int kt=0; kt<14; kt++){
    int k0 = kt*32;
    int kc = k0 + seg*8;
    #pragma unroll
    for (int rr=0; rr<2; rr++){
      int r = r0 + rr*64;
      int row = m0 + r;
      const float* src;
      if (kc < 256)      src = loct  + (size_t)loc[row]*256 + kc;
      else if (kc < 320) src = usert + (size_t)usr[row]*64 + (kc-256);
      else if (kc < 384) { int s = sm[row]; int hh = s/60; if (hh>24) hh=24; if (hh<0) hh=0;
                           src = hourt + (size_t)hh*64 + (kc-320); }
      else               src = wdt   + (size_t)wdy[row]*64 + (kc-384);
      float4 v0 = *(const float4*)(src);
      float4 v1 = *(const float4*)(src+4);
      short8 pk;
      pk[0]=f2bf_(v0.x); pk[1]=f2bf_(v0.y); pk[2]=f2bf_(v0.z); pk[3]=f2bf_(v0.w);
      pk[4]=f2bf_(v1.x); pk[5]=f2bf_(v1.y); pk[6]=f2bf_(v1.z); pk[7]=f2bf_(v1.w);
      *(short8*)&As[r][seg*8] = pk;
    }
    __syncthreads();
    short8 bfrag[4], afrag[4];
    #pragma unroll
    for (int nt=0; nt<4; nt++)
      bfrag[nt] = *(const short8*)(Wihbf + (size_t)(n0+nw+nt*16+l16)*KX + k0 + quad*8);
    #pragma unroll
    for (int mt=0; mt<4; mt++)
      afrag[mt] = *(const short8*)&As[mw+mt*16+l16][quad*8];
    #pragma unroll
    for (int mt=0; mt<4; mt++)
      #pragma unroll
      for (int nt=0; nt<4; nt++)
        acc[mt][nt] = __builtin_amdgcn_mfma_f32_16x16x32_bf16(afrag[mt], bfrag[nt], acc[mt][nt], 0, 0, 0);
    __syncthreads();
  }
  #pragma unroll
  for (int nt=0; nt<4; nt++){
    int col = n0 + nw + nt*16 + l16;
    float bv = btot[col];
    #pragma unroll
    for (int mt=0; mt<4; mt++){
      #pragma unroll
      for (int i=0; i<4; i++){
        int row = m0 + mw + mt*16 + quad*4 + i;   // row = b*S + t
        int b = row >> 8, t = row & 255;
        Gx[((size_t)t*B_ + b)*G4 + col] = f2bf_(acc[mt][nt][i] + bv);
      }
    }
  }
}

// ---- persistent LSTM: all 256 steps in one dispatch, grid barrier per step ----
// 128 blocks = (bt 0..15)x(dt 0..7): 32 batch rows x 32 hidden dims per block.
// W_hh slice LDS-resident (fragment-major, 64 KB). c in registers.
__global__ __launch_bounds__(256,1) void k_lstm_all(
    const unsigned short* __restrict__ Gx, const unsigned short* __restrict__ Whhbf,
    unsigned short* __restrict__ hbf0, unsigned short* __restrict__ hbf1,
    float* __restrict__ ctx, const int* __restrict__ slens, int* flags){
  __shared__ unsigned short WsF[32768];    // 64 KB, fragment-major
  int tid = threadIdx.x;
  int bx = blockIdx.x;
  int b0 = (bx >> 3) * 32;                 // batch tile
  int d0 = (bx & 7) * 32;                  // hidden-dim tile
  int w = tid>>6, lane = tid&63;
  int quad = lane>>4, l16 = lane&15;
  int dwi = w & 1, mw = (w>>1)*16;

  // stage W_hh slice into LDS, fragment-major:
  // frag f = ((kt*4+q)*2+dwi)*64 + lane  holds Whh[q*256+d0+dwi*16+l16][kt*32+quad*8 ..+8]
  #pragma unroll
  for (int j=0; j<16; j++){
    int f = tid + 256*j;
    int fl = f & 63;
    int fdwi = (f>>6)&1, fq = (f>>7)&3, fkt = f>>9;
    int grow = fq*256 + d0 + fdwi*16 + (fl&15);
    int gk = fkt*32 + (fl>>4)*8;
    *(short8*)&WsF[f*8] = *(const short8*)(Whhbf + (size_t)grow*D_ + gk);
  }
  __syncthreads();

  // per-lane persistent state
  f32x4 creg = {0.f,0.f,0.f,0.f};
  int d = d0 + dwi*16 + l16;
  int brow[4], sl[4];
  #pragma unroll
  for (int i=0;i<4;i++){ brow[i] = b0 + mw + quad*4 + i; sl[i] = slens[brow[i]]; }

  // prefetch Gx for t=0
  unsigned short gxr[4][4];
  #pragma unroll
  for (int q=0;q<4;q++)
    #pragma unroll
    for (int i=0;i<4;i++)
      gxr[q][i] = Gx[((size_t)0*B_ + brow[i])*G4 + q*256 + d];

  for (int t=0; t<S_; t++){
    const unsigned short* hi = (t & 1) ? hbf1 : hbf0;
    unsigned short*       ho = (t & 1) ? hbf0 : hbf1;
    f32x4 acc[4] = {};
    #pragma unroll
    for (int kt=0; kt<8; kt++){
      short8 af = *(const short8*)(hi + (size_t)(b0+mw+l16)*D_ + kt*32 + quad*8);
      #pragma unroll
      for (int q=0; q<4; q++){
        short8 bf = *(const short8*)&WsF[((((kt*4+q)*2)+dwi)*64 + lane)*8];
        acc[q] = __builtin_amdgcn_mfma_f32_16x16x32_bf16(af, bf, acc[q], 0, 0, 0);
      }
    }
    #pragma unroll
    for (int i=0; i<4; i++){
      int b = brow[i];
      float gi = acc[0][i] + bf2f_(gxr[0][i]);
      float gf = acc[1][i] + bf2f_(gxr[1][i]);
      float gg = acc[2][i] + bf2f_(gxr[2][i]);
      float go = acc[3][i] + bf2f_(gxr[3][i]);
      float cn = sigmoidf_(gf)*creg[i] + sigmoidf_(gi)*tanhf(gg);
      float hn = sigmoidf_(go)*tanhf(cn);
      creg[i] = cn;
      ho[(size_t)b*D_ + d] = f2bf_(hn);
      if (t == sl[i]) ctx[(size_t)b*D_ + d] = hn;
    }
    if (t < S_-1){
      // prefetch next step's Gx (independent of h) — hides HBM latency under barrier
      #pragma unroll
      for (int q=0;q<4;q++)
        #pragma unroll
        for (int i=0;i<4;i++)
          gxr[q][i] = Gx[((size_t)(t+1)*B_ + brow[i])*G4 + q*256 + d];
      // ---- grid barrier ----
      __syncthreads();
      if (tid == 0){
        __threadfence();
        __hip_atomic_store(&flags[bx*16], t+1, __ATOMIC_RELEASE, __HIP_MEMORY_SCOPE_AGENT);
      }
      if (tid < 64){
        int tp1 = t+1;
        for(;;){
          int f0 = __hip_atomic_load(&flags[tid*16],      __ATOMIC_ACQUIRE, __HIP_MEMORY_SCOPE_AGENT);
          int f1 = __hip_atomic_load(&flags[(tid+64)*16], __ATOMIC_ACQUIRE, __HIP_MEMORY_SCOPE_AGENT);
          if (__all(f0 >= tp1 && f1 >= tp1)) break;
          __builtin_amdgcn_s_sleep(1);
        }
      }
      __syncthreads();
    }
  }
}

// ---- newhid = gelu(ctx @ np_W1^T + np_b1); mix = sigmoid(ctx . mx_W + mx_b)*0.9+0.05 ----
__global__ void k_post1(const float* __restrict__ ctx, const float* __restrict__ W1,
                        const float* __restrict__ b1, const float* __restrict__ mxW,
                        const float* __restrict__ mxb, float* newhid, float* mixv){
  __shared__ float cs[256];
  __shared__ float red[256];
  int b = blockIdx.x, tid = threadIdx.x;
  cs[tid] = ctx[(size_t)b*D_ + tid];
  __syncthreads();
  float a = b1[tid];
  const float* wr = W1 + (size_t)tid*D_;
  for (int k=0; k<D_; k++) a += cs[k]*wr[k];
  newhid[(size_t)b*D_ + tid] = geluf_(a);
  red[tid] = cs[tid]*mxW[tid];
  __syncthreads();
  for (int s=128; s>0; s>>=1){ if (tid<s) red[tid]+=red[tid+s]; __syncthreads(); }
  if (tid==0) mixv[b] = sigmoidf_(red[0]+mxb[0])*0.9f + 0.05f;
}

// ---- recent-location scores + dedup/keep ----
__global__ void k_recent(const int* __restrict__ loc, const int* __restrict__ sm,
                         const int* __restrict__ slens, const float* __restrict__ loct,
                         const float* __restrict__ W1, const float* __restrict__ b1,
                         const float* __restrict__ W2, const float* __restrict__ b2,
                         float* scores, int* rlocs, int* keep){
  __shared__ int rl[5], vs[5];
  __shared__ float td[5];
  __shared__ float red[128];
  int b = blockIdx.x, tid = threadIdx.x;
  int sl = slens[b];
  if (tid < 5){
    int idx = sl - tid;
    int v = idx >= 0;
    int ic = v ? idx : 0;
    rl[tid] = loc[b*S_ + ic];
    vs[tid] = v;
    int cur = sm[b*S_ + sl];
    td[tid] = (float)(cur - sm[b*S_ + ic]) * (1.0f/1440.0f);
  }
  __syncthreads();
  for (int j=0; j<5; j++){
    const float* lrow = loct + (size_t)rl[j]*D_;
    const float* wr = W1 + (size_t)tid*258;
    float a = b1[tid];
    for (int k=0; k<D_; k++) a += lrow[k]*wr[k];
    a += td[j]*wr[256] + (float)j*wr[257];
    red[tid] = geluf_(a)*W2[tid];
    __syncthreads();
    for (int s=64; s>0; s>>=1){ if (tid<s) red[tid]+=red[tid+s]; __syncthreads(); }
    if (tid==0) scores[b*5+j] = red[0] + b2[0];
    __syncthreads();
  }
  if (tid==0){
    for (int j=0; j<5; j++){
      int dup = 0;
      for (int k=0; k<j; k++) dup |= (rl[j]==rl[k]) && vs[k];
      keep[b*5+j] = vs[j] && !dup;
      rlocs[b*5+j] = rl[j];
    }
  }
}

// ---- big fused head: out[b,l] = mix*NEG + (1-mix)*(newhid[b].np_W2[l] + np_b2[l]) ----
__global__ __launch_bounds__(256) void k_final(const float* __restrict__ newhid,
    const float* __restrict__ W2, const float* __restrict__ b2,
    const float* __restrict__ mixv, float* __restrict__ out){
  __shared__ float Hs[16][256];
  __shared__ float Wl[64][65];
  int tid = threadIdx.x;
  int l0 = blockIdx.x*64, b0 = blockIdx.y*16;
  int ll = tid & 63, bq = tid >> 6;
  #pragma unroll
  for (int r=0; r<16; r++) Hs[r][tid] = newhid[(size_t)(b0+r)*D_ + tid];
  float acc[4] = {0.f,0.f,0.f,0.f};
  for (int kt=0; kt<4; kt++){
    int k0 = kt*64;
    __syncthreads();
    #pragma unroll
    for (int r=0; r<4; r++){
      int row = 4*r + bq;
      int l = l0 + row;
      Wl[row][ll] = (l < NLOC) ? W2[(size_t)l*D_ + k0 + ll] : 0.f;
    }
    __syncthreads();
    #pragma unroll
    for (int kk=0; kk<64; kk++){
      float wv = Wl[ll][kk];
      #pragma unroll
      for (int bi=0; bi<4; bi++) acc[bi] += wv * Hs[bq*4+bi][k0+kk];
    }
  }
  int l = l0 + ll;
  if (l < NLOC){
    float bias = b2[l];
    #pragma unroll
    for (int bi=0; bi<4; bi++){
      int b = b0 + bq*4 + bi;
      float mx = mixv[b];
      out[(size_t)b*NLOC + l] = mx*NEGV + (1.0f-mx)*(acc[bi] + bias);
    }
  }
}

// ---- overwrite kept recent locations ----
__global__ void k_scatter(const float* __restrict__ newhid, const float* __restrict__ W2,
                          const float* __restrict__ b2, const float* __restrict__ mixv,
                          const float* __restrict__ scores, const int* __restrict__ rlocs,
                          const int* __restrict__ keep, float* out){
  int b = blockIdx.x, lane = threadIdx.x;
  float mx = mixv[b];
  for (int j=0; j<5; j++){
    if (!keep[b*5+j]) continue;
    int rl = rlocs[b*5+j];
    const float* wr = W2 + (size_t)rl*D_;
    const float* hr = newhid + (size_t)b*D_;
    float a = 0.f;
    #pragma unroll
    for (int q=0; q<4; q++){ int k = lane + 64*q; a += hr[k]*wr[k]; }
    #pragma unroll
    for (int off=32; off>0; off>>=1) a += __shfl_xor(a, off, 64);
    if (lane==0)
      out[(size_t)b*NLOC + rl] = mx*scores[b*5+j] + (1.0f-mx)*(a + b2[rl]);
  }
}

extern "C" void kernel_launch(void* const* d_in, const int* in_sizes, int n_in,
                              void* d_out, int out_size, void* d_ws, size_t ws_size,
                              hipStream_t stream){
  const int* locations   = (const int*)d_in[0];
  const int* users       = (const int*)d_in[1];
  const int* weekdays    = (const int*)d_in[2];
  const int* start_mins  = (const int*)d_in[3];
  const void* mask       = d_in[4];
  const float* loc_table = (const float*)d_in[5];
  const float* user_table= (const float*)d_in[6];
  const float* hour_table= (const float*)d_in[7];
  const float* wd_table  = (const float*)d_in[8];
  const float* W_ih      = (const float*)d_in[9];
  const float* W_hh      = (const float*)d_in[10];
  const float* b_ih      = (const float*)d_in[11];
  const float* b_hh      = (const float*)d_in[12];
  const float* sc_W1     = (const float*)d_in[13];
  const float* sc_b1     = (const float*)d_in[14];
  const float* sc_W2     = (const float*)d_in[15];
  const float* sc_b2     = (const float*)d_in[16];
  const float* np_W1     = (const float*)d_in[17];
  const float* np_b1     = (const float*)d_in[18];
  const float* np_W2     = (const float*)d_in[19];
  const float* np_b2     = (const float*)d_in[20];
  const float* mx_W      = (const float*)d_in[21];
  const float* mx_b      = (const float*)d_in[22];
  float* out = (float*)d_out;

  char* w = (char*)d_ws;
  size_t o = 0;
  auto alloc = [&](size_t bytes)->void*{ void* p = w + o; o += (bytes + 255) & ~(size_t)255; return p; };
  unsigned short* Gx    = (unsigned short*)alloc((size_t)B_*S_*G4*sizeof(short)); // 268 MB, [t][b][1024]
  unsigned short* Wihbf = (unsigned short*)alloc((size_t)G4*KX*sizeof(short));
  unsigned short* Whhbf = (unsigned short*)alloc((size_t)G4*D_*sizeof(short));
  float* btot   = (float*)alloc((size_t)G4*sizeof(float));
  unsigned short* hbf0 = (unsigned short*)alloc((size_t)B_*D_*sizeof(short));
  unsigned short* hbf1 = (unsigned short*)alloc((size_t)B_*D_*sizeof(short));
  float* ctx    = (float*)alloc((size_t)B_*D_*sizeof(float));
  float* newhid = (float*)alloc((size_t)B_*D_*sizeof(float));
  float* mixv   = (float*)alloc((size_t)B_*sizeof(float));
  float* scores = (float*)alloc((size_t)B_*5*sizeof(float));
  int*   slens  = (int*)alloc((size_t)B_*sizeof(int));
  int*   rlocs  = (int*)alloc((size_t)B_*5*sizeof(int));
  int*   keep   = (int*)alloc((size_t)B_*5*sizeof(int));
  int*   flags  = (int*)alloc((size_t)NBLK*16*sizeof(int));
  int*   flag   = (int*)alloc(sizeof(int));

  k_init<<<512, 256, 0, stream>>>(hbf0, flags, flag);
  k_detect<<<512, 256, 0, stream>>>((const unsigned char*)mask, flag);
  k_seqlen<<<2, 256, 0, stream>>>(mask, flag, slens);
  k_buildw<<<1792, 256, 0, stream>>>(W_ih, W_hh, b_ih, b_hh, Wihbf, Whhbf, btot);
  k_gx<<<dim3(8,1024), 256, 0, stream>>>(locations, users, weekdays, start_mins,
                                         loc_table, user_table, hour_table, wd_table,
                                         Wihbf, btot, Gx);
  k_lstm_all<<<NBLK, 256, 0, stream>>>(Gx, Whhbf, hbf0, hbf1, ctx, slens, flags);
  k_post1<<<512, 256, 0, stream>>>(ctx, np_W1, np_b1, mx_W, mx_b, newhid, mixv);
  k_recent<<<512, 128, 0, stream>>>(locations, start_mins, slens, loc_table,
                                    sc_W1, sc_b1, sc_W2, sc_b2, scores, rlocs, keep);
  k_final<<<dim3(782,32), 256, 0, stream>>>(newhid, np_W2, np_b2, mixv, out);
  k_scatter<<<512, 64, 0, stream>>>(newhid, np_W2, np_b2, mixv, scores, rlocs, keep, out);
}